// Round 11
// baseline (76.742 us; speedup 1.0000x reference)
//
#include <hip/hip_runtime.h>

// Problem constants
#define MM 15   // max_peptide_size
#define RR 64   // aa_rep_size
#define PP 34   // pocket positions
#define FF 9    // filter size
#define AA 20   // alphabet size
#define OW 72   // RR + FF - 1
#define SP 84   // s_s row stride (floats), 16B-aligned
#define KS 12   // kernels row stride (floats), 16B-aligned
#define AJ 16   // adj-float row stride (floats), 16B-aligned

__global__ __launch_bounds__(256)
void ppc_kernel(const float* __restrict__ pe,      // [B, M, R]
                const int*   __restrict__ idx,     // [B, P]
                const int*   __restrict__ adj,     // [B, P, M]
                const float* __restrict__ kernels, // [A, F]
                float*       __restrict__ out)     // [B, P, OW]
{
    const int b = blockIdx.x;
    const int t = threadIdx.x;

    __shared__ float s_pe[MM * RR];    // 960 f
    __shared__ float s_kern[AA * KS];  // 240 f
    __shared__ float s_adjf[PP * AJ];  // 544 f (col 15 unused)
    __shared__ int   s_idx[PP];
    __shared__ float s_s[PP * SP];     // 2856 f, zero-padded conv rows

    const float* peb  = pe  + (size_t)b * (MM * RR);
    const int*   adjb = adj + (size_t)b * (PP * MM);

    // ---- staging (coalesced / vectorized)
    if (t < (MM * RR) / 4)
        *(float4*)&s_pe[t * 4] = *(const float4*)&peb[t * 4];
    if (t < AA * FF) {
        int a = (unsigned)t / FF, j = t - a * FF;
        s_kern[a * KS + j] = kernels[t];
    }
    for (int i = t; i < PP * MM; i += 256) {
        int p = (unsigned)i / MM, m = i - p * MM;
        s_adjf[p * AJ + m] = (float)adjb[i];
    }
    if (t < PP) s_idx[t] = idx[(size_t)b * PP + t];
    if (t < PP * 5) {   // conv zero pads: dwords {0..7} and {72..83} per row, as float4
        int p = (unsigned)t / 5, k = t - p * 5;
        int off = p * SP + (k < 2 ? k * 4 : 72 + (k - 2) * 4);
        *(float4*)&s_s[off] = make_float4(0.f, 0.f, 0.f, 0.f);
    }
    __syncthreads();

    // ---- Phase B: wave w owns rows p = w, w+4, ..., w+32; lane = r.
    // pe: 15 x ds_read_b32 (2-way, free). adj: single-address b128 broadcasts.
    {
        const int w = t >> 6;     // wave id (uniform)
        const int r = t & 63;     // lane = representation index
        float pv[MM];
        #pragma unroll
        for (int m = 0; m < MM; ++m) pv[m] = s_pe[m * RR + r];
        #pragma unroll
        for (int j = 0; j < 9; ++j) {
            const int p = w + 4 * j;
            if (p < PP) {                       // wave-uniform branch
                const float* g = &s_adjf[p * AJ];
                const float4 g0 = *(const float4*)&g[0];
                const float4 g1 = *(const float4*)&g[4];
                const float4 g2 = *(const float4*)&g[8];
                const float4 g3 = *(const float4*)&g[12];   // .w unused
                float acc;
                acc  = g0.x * pv[0]  + g0.y * pv[1]  + g0.z * pv[2]  + g0.w * pv[3];
                acc += g1.x * pv[4]  + g1.y * pv[5]  + g1.z * pv[6]  + g1.w * pv[7];
                acc += g2.x * pv[8]  + g2.y * pv[9]  + g2.z * pv[10] + g2.w * pv[11];
                acc += g3.x * pv[12] + g3.y * pv[13] + g3.z * pv[14];
                s_s[p * SP + 8 + r] = acc;      // banks (20p+8+r)%32: 2-way, free
            }
        }
    }
    __syncthreads();

    float* outb = out + (size_t)b * (PP * OW);
    const int c  = t & 15;   // r-quad within row
    const int q  = t >> 4;   // q-group owns p = q, q+16, q+32
    const int r0 = c << 2;

    // ---- Phase C: lane c -> o0 = 4c (c<2 also o0 = 64+4c); aligned b128 reads
    auto do_p = [&](const int p) {
        float kf[FF];
        {
            const float* kb = &s_kern[s_idx[p] * KS];   // group-uniform broadcast
            const float4 k0 = *(const float4*)&kb[0];
            const float4 k1 = *(const float4*)&kb[4];
            kf[0]=k0.x; kf[1]=k0.y; kf[2]=k0.z; kf[3]=k0.w;
            kf[4]=k1.x; kf[5]=k1.y; kf[6]=k1.z; kf[7]=k1.w;
            kf[8]=kb[8];
        }
        const float* row = &s_s[p * SP];
        {
            float w[12];
            *(float4*)&w[0] = *(const float4*)&row[r0];
            *(float4*)&w[4] = *(const float4*)&row[r0 + 4];
            *(float4*)&w[8] = *(const float4*)&row[r0 + 8];
            float ax=0, ay=0, az=0, aw=0;
            #pragma unroll
            for (int j = 0; j < FF; ++j) {
                const float k = kf[j];
                ax += k * w[8  - j];
                ay += k * w[9  - j];
                az += k * w[10 - j];
                aw += k * w[11 - j];
            }
            *(float4*)&outb[p * OW + r0] = make_float4(ax, ay, az, aw);
        }
        if (c < 2) {                      // tail quads o0 = 64, 68
            const int o0 = 64 + r0;
            float w[12];
            *(float4*)&w[0] = *(const float4*)&row[o0];
            *(float4*)&w[4] = *(const float4*)&row[o0 + 4];
            *(float4*)&w[8] = *(const float4*)&row[o0 + 8];
            float ax=0, ay=0, az=0, aw=0;
            #pragma unroll
            for (int j = 0; j < FF; ++j) {
                const float k = kf[j];
                ax += k * w[8  - j];
                ay += k * w[9  - j];
                az += k * w[10 - j];
                aw += k * w[11 - j];
            }
            *(float4*)&outb[p * OW + o0] = make_float4(ax, ay, az, aw);
        }
    };

    do_p(q);
    do_p(q + 16);
    if (q + 32 < PP) do_p(q + 32);
}

extern "C" void kernel_launch(void* const* d_in, const int* in_sizes, int n_in,
                              void* d_out, int out_size, void* d_ws, size_t ws_size,
                              hipStream_t stream) {
    const float* pe      = (const float*)d_in[0]; // [B,M,R] f32
    const int*   idx     = (const int*)  d_in[1]; // [B,P]   i32
    const int*   adj     = (const int*)  d_in[2]; // [B,P,M] i32
    const float* kernels = (const float*)d_in[3]; // [A,F]   f32
    float*       out     = (float*)d_out;

    const int B = in_sizes[0] / (MM * RR);
    ppc_kernel<<<B, 256, 0, stream>>>(pe, idx, adj, kernels, out);
}

// Round 13
// 73.723 us; speedup vs baseline: 1.0409x; 1.0409x over previous
//
#include <hip/hip_runtime.h>

// Problem constants
#define MM 15   // max_peptide_size
#define RR 64   // aa_rep_size
#define PP 34   // pocket positions
#define FF 9    // filter size
#define AA 20   // alphabet size
#define OW 72   // RR + FF - 1
#define SP 84   // s_s row stride (floats), 16B-aligned
#define KS 12   // kernels row stride (floats), 16B-aligned
#define AJ 16   // adj-float row stride (floats), 16B-aligned

// One block per sample. 256 threads = 4 waves.
// Wave w owns rows p = w, w+4, ..., w+32 through BOTH phases -> no barrier
// between Phase B and Phase C (intra-wave LDS RAW only needs lgkmcnt).
__global__ __launch_bounds__(256)
void ppc_kernel(const float* __restrict__ pe,      // [B, M, R]
                const int*   __restrict__ idx,     // [B, P]
                const int*   __restrict__ adj,     // [B, P, M]
                const float* __restrict__ kernels, // [A, F]
                float*       __restrict__ out)     // [B, P, OW]
{
    const int b = blockIdx.x;
    const int t = threadIdx.x;

    __shared__ float s_kern[AA * KS];  // 240 f
    __shared__ float s_adjf[PP * AJ];  // 544 f (col 15 never read)
    __shared__ int   s_idx[PP];
    __shared__ float s_s[PP * SP];     // 2856 f, zero-padded conv rows
    // total ~14.7 KB

    const float* peb  = pe  + (size_t)b * (MM * RR);
    const int*   adjb = adj + (size_t)b * (PP * MM);

    const int w    = t >> 6;   // wave id
    const int lane = t & 63;   // lane = representation index r

    // ---- Phase-B pe reads straight from global (coalesced, L1/L2-hot; no LDS)
    float pv[MM];
    #pragma unroll
    for (int m = 0; m < MM; ++m) pv[m] = peb[m * RR + lane];

    // ---- tiny staging: kernels (re-strided), adj->float, idx, s_s zero pads
    if (t < AA * FF) {
        int a = (unsigned)t / FF, j = t - a * FF;
        s_kern[a * KS + j] = kernels[t];
    }
    for (int i = t; i < PP * MM; i += 256) {
        int p = (unsigned)i / MM, m = i - p * MM;
        s_adjf[p * AJ + m] = (float)adjb[i];
    }
    if (t < PP) s_idx[t] = idx[(size_t)b * PP + t];
    if (t < PP * 5) {   // conv zero pads: dwords {0..7} and {72..83} per row
        int p = (unsigned)t / 5, k = t - p * 5;
        int off = p * SP + (k < 2 ? k * 4 : 72 + (k - 2) * 4);
        *(float4*)&s_s[off] = make_float4(0.f, 0.f, 0.f, 0.f);
    }
    __syncthreads();   // the only barrier

    // ---- Phase B: s[p][8+lane] for the wave's rows; adj via broadcast b128
    #pragma unroll
    for (int j = 0; j < 9; ++j) {
        const int p = w + 4 * j;          // wave-uniform
        if (p < PP) {
            const float* g = &s_adjf[p * AJ];
            const float4 g0 = *(const float4*)&g[0];
            const float4 g1 = *(const float4*)&g[4];
            const float4 g2 = *(const float4*)&g[8];
            const float4 g3 = *(const float4*)&g[12];   // .w unused
            float acc;
            acc  = g0.x * pv[0]  + g0.y * pv[1]  + g0.z * pv[2]  + g0.w * pv[3];
            acc += g1.x * pv[4]  + g1.y * pv[5]  + g1.z * pv[6]  + g1.w * pv[7];
            acc += g2.x * pv[8]  + g2.y * pv[9]  + g2.z * pv[10] + g2.w * pv[11];
            acc += g3.x * pv[12] + g3.y * pv[13] + g3.z * pv[14];
            s_s[p * SP + 8 + lane] = acc;
        }
    }
    // no __syncthreads: Phase C below reads only rows this wave wrote
    // (compiler inserts the required s_waitcnt lgkmcnt before the reads)

    float* outb = out + (size_t)b * (PP * OW);

    // ---- Phase C: 3 uniform passes; lane -> (rowk = lane/18, o0 = 4*(lane%18))
    const int rowk = (unsigned)lane / 18u;       // 0..3 (3 = idle)
    const int q18  = lane - 18 * rowk;
    const int o0   = q18 << 2;                   // 0..68

    #pragma unroll
    for (int k = 0; k < 3; ++k) {
        const int j = 3 * k + rowk;              // 0..8 for active lanes
        const int p = w + 4 * j;
        if (rowk < 3 && p < PP) {
            const float* kb = &s_kern[s_idx[p] * KS];
            const float4 k0 = *(const float4*)&kb[0];
            const float4 k1 = *(const float4*)&kb[4];
            float kf[FF];
            kf[0]=k0.x; kf[1]=k0.y; kf[2]=k0.z; kf[3]=k0.w;
            kf[4]=k1.x; kf[5]=k1.y; kf[6]=k1.z; kf[7]=k1.w;
            kf[8]=kb[8];

            const float* row = &s_s[p * SP];
            float wv[12];
            *(float4*)&wv[0] = *(const float4*)&row[o0];      // aligned b128
            *(float4*)&wv[4] = *(const float4*)&row[o0 + 4];
            *(float4*)&wv[8] = *(const float4*)&row[o0 + 8];

            float ax=0, ay=0, az=0, aw=0;
            #pragma unroll
            for (int jj = 0; jj < FF; ++jj) {
                const float kk = kf[jj];
                ax += kk * wv[8  - jj];
                ay += kk * wv[9  - jj];
                az += kk * wv[10 - jj];
                aw += kk * wv[11 - jj];
            }
            *(float4*)&outb[p * OW + o0] = make_float4(ax, ay, az, aw);
        }
    }
}

extern "C" void kernel_launch(void* const* d_in, const int* in_sizes, int n_in,
                              void* d_out, int out_size, void* d_ws, size_t ws_size,
                              hipStream_t stream) {
    const float* pe      = (const float*)d_in[0]; // [B,M,R] f32
    const int*   idx     = (const int*)  d_in[1]; // [B,P]   i32
    const int*   adj     = (const int*)  d_in[2]; // [B,P,M] i32
    const float* kernels = (const float*)d_in[3]; // [A,F]   f32
    float*       out     = (float*)d_out;

    const int B = in_sizes[0] / (MM * RR);
    ppc_kernel<<<B, 256, 0, stream>>>(pe, idx, adj, kernels, out);
}